// Round 15
// baseline (198.106 us; speedup 1.0000x reference)
//
#include <hip/hip_runtime.h>
#include <hip/hip_bf16.h>

#define NB 8
#define NN 256
#define NL 32
#define NQ 8192              // NN*NL
#define NH 64
#define SL ((size_t)NQ * NN) // elements per (b,k) T1 slab

typedef __attribute__((ext_vector_type(8))) short short8v;
typedef __attribute__((ext_vector_type(4))) float float4v;
typedef __attribute__((ext_vector_type(16))) float float16v;

static __device__ __forceinline__ ushort f2bf(float f) {
  __hip_bfloat16 h = __float2bfloat16(f);
  return *reinterpret_cast<const ushort*>(&h);
}
static __device__ __forceinline__ uint packbf(float a, float b) {
  return (uint)f2bf(a) | ((uint)f2bf(b) << 16);
}
static __device__ __forceinline__ void gld_lds16(const void* g, void* l) {
  __builtin_amdgcn_global_load_lds(
      (const __attribute__((address_space(1))) unsigned int*)g,
      (__attribute__((address_space(3))) unsigned int*)l, 16, 0, 0);
}

// ---------------------------------------------------------------------------
// Gt[k][m][n] = bf16(G[k][n][m])
// ---------------------------------------------------------------------------
__global__ __launch_bounds__(256) void prep_g(const float* __restrict__ G,
                                              ushort* __restrict__ Gt) {
  __shared__ float t[32][33];
  const int k = blockIdx.z, m0 = blockIdx.x * 32, n0 = blockIdx.y * 32;
  const int tid = threadIdx.x;
  const int c = tid & 31, r8 = tid >> 5;
#pragma unroll
  for (int i = 0; i < 4; ++i) {
    int r = r8 + i * 8;
    t[r][c] = G[((size_t)k * NN + n0 + r) * NN + m0 + c];
  }
  __syncthreads();
#pragma unroll
  for (int i = 0; i < 4; ++i) {
    int rm = r8 + i * 8;
    Gt[((size_t)k * NN + m0 + rm) * NN + n0 + c] = f2bf(t[c][rm]);
  }
}

// ---------------------------------------------------------------------------
// WtF: stage-3 A fragments in lane order. Entry e = ((kj*2+kp)*2+hb)*64+lane,
// 16B granule = 8 bf16 of W rows (kj*32+kp*16+(lane>>5)*8 + 0..7), col h.
// ---------------------------------------------------------------------------
__global__ __launch_bounds__(256) void prep_wf(const float* __restrict__ W,
                                               ushort* __restrict__ WtF) {
  const int tid = threadIdx.x;
  for (int e = tid; e < 9 * 2 * 2 * 64; e += 256) {
    const int ln = e & 63, hb = (e >> 6) & 1, kp = (e >> 7) & 1, kj = e >> 8;
    const int h = hb * 32 + (ln & 31);
    const int c0 = kj * 32 + kp * 16 + (ln >> 5) * 8;
    ushort v[8];
#pragma unroll
    for (int i = 0; i < 8; ++i) v[i] = f2bf(W[(size_t)(c0 + i) * NH + h]);
    *(ulong2*)(WtF + (size_t)e * 8) = *(ulong2*)v;
  }
}

// ---------------------------------------------------------------------------
// Xt[b][q'][n] = bf16(X[b][n][q]),  q = c*32+l,  q' = l*256+c
// ---------------------------------------------------------------------------
__global__ __launch_bounds__(256) void prep_x(const float* __restrict__ X,
                                              ushort* __restrict__ Xt) {
  __shared__ float t[32][33];
  const int qt = blockIdx.x;
  const int n0 = blockIdx.y * 32;
  const int b  = blockIdx.z;
  const int tid = threadIdx.x;
  const int c = tid & 31, r8 = tid >> 5;
  const float* Xb = X + (size_t)b * NN * NQ;
  ushort* Xo = Xt + (size_t)b * SL;
  const size_t q0 = (size_t)qt * 32;
#pragma unroll
  for (int i = 0; i < 4; ++i) {
    int r = r8 + i * 8;
    t[r][c] = Xb[(size_t)(n0 + r) * NQ + q0 + c];
  }
  __syncthreads();
#pragma unroll
  for (int i = 0; i < 4; ++i) {
    int l = r8 + i * 8;
    Xo[((size_t)l * NN + qt) * NN + n0 + c] = f2bf(t[c][l]);
  }
}

// ---------------------------------------------------------------------------
// Stage 1 GEMM v2 (gemm2): T1[z][m][q'] = Gt[z%3][m][:] . Xt[z/3][q'][:]
// Quarter-K ping-pong via global_load_lds, 256B-pitch 2-row-packed
// zero-conflict LDS, 4 waves (2x2), wave tile 64x64 of 32x32x16 MFMA.
// ---------------------------------------------------------------------------
__global__ __launch_bounds__(256, 2) void gemm2(
    const ushort* __restrict__ Gt, const ushort* __restrict__ Xt,
    ushort* __restrict__ T1) {
  __shared__ ulong2 LDSQ[4096];              // 64 KB
  char* base = (char*)LDSQ;

  const int tid = threadIdx.x;
  const int z = blockIdx.z;                  // b*3 + k
  const ushort* Ab = Gt + (size_t)(z % 3) * NN * NN +
                     (size_t)blockIdx.y * 128 * NN;
  const ushort* Bb = Xt + (size_t)(z / 3) * SL +
                     (size_t)blockIdx.x * 128 * NN;
  ushort* Cb = T1 + (size_t)z * SL;

  const int lane = tid & 63;
  const int w  = tid >> 6;
  const int l5 = lane & 31;
  const int h5 = lane >> 5;
  const int wr = (w >> 1) * 64;              // m within tile
  const int wc = (w & 1) * 64;               // q' within tile

  auto stage = [&](int q, int qb) {
    const ushort* a = Ab + q * 64;
    const ushort* bsrc = Bb + q * 64;
    char* d1 = base + qb + ((tid & 192) << 4);
    char* d2 = d1 + 16384;
#pragma unroll
    for (int i = 0; i < 4; ++i) {
      const int gl = i * 256 + tid;          // linear granule 0..1023
      const int R  = gl >> 4;
      const int sd = (gl & 15) ^ (R & 15);
      const int dr = 2 * R + (sd >> 3);      // data row 0..127
      const int g  = sd & 7;
      gld_lds16(a + (size_t)dr * 256 + g * 8, d1 + (i << 12));
      gld_lds16(bsrc + (size_t)dr * 256 + g * 8, d2 + (i << 12));
    }
  };
  auto ldv = [&](int qb, int toff, int row, int gq) -> short8v {
    const int R = row >> 1;
    const int s = (((row & 1) << 3) + gq) ^ (R & 15);
    return *(const short8v*)(base + qb + toff + (((R << 4) + s) << 4));
  };

  float16v acc[2][2] = {};

  stage(0, 0);

  for (int q = 0; q < 4; ++q) {
    const int qb = (q & 1) << 15;
    __syncthreads();
    if (q + 1 < 4) stage(q + 1, qb ^ 32768);
    __builtin_amdgcn_s_setprio(1);
#pragma unroll
    for (int ks = 0; ks < 4; ++ks) {
      const int gq = 2 * ks + h5;
      short8v a0 = ldv(qb, 0,     wr + l5,      gq);
      short8v a1 = ldv(qb, 0,     wr + 32 + l5, gq);
      short8v b0 = ldv(qb, 16384, wc + l5,      gq);
      short8v b1 = ldv(qb, 16384, wc + 32 + l5, gq);
      acc[0][0] = __builtin_amdgcn_mfma_f32_32x32x16_bf16(a0, b0, acc[0][0], 0, 0, 0);
      acc[0][1] = __builtin_amdgcn_mfma_f32_32x32x16_bf16(a0, b1, acc[0][1], 0, 0, 0);
      acc[1][0] = __builtin_amdgcn_mfma_f32_32x32x16_bf16(a1, b0, acc[1][0], 0, 0, 0);
      acc[1][1] = __builtin_amdgcn_mfma_f32_32x32x16_bf16(a1, b1, acc[1][1], 0, 0, 0);
    }
    __builtin_amdgcn_s_setprio(0);
  }

  // Epilogue: D-layout col = lane&31, row = (r&3) + 8*(r>>2) + 4*h5 (m101).
#pragma unroll
  for (int ms = 0; ms < 2; ++ms) {
#pragma unroll
    for (int ds = 0; ds < 2; ++ds) {
      ushort* cp = Cb +
          (size_t)(blockIdx.y * 128 + wr + ms * 32 + 4 * h5) * NQ +
          blockIdx.x * 128 + wc + ds * 32 + l5;
#pragma unroll
      for (int r = 0; r < 16; ++r) {
        const int row = (r & 3) + 8 * (r >> 2);
        cp[(size_t)row * NQ] = f2bf(acc[ms][ds][r]);
      }
    }
  }
}

// ---------------------------------------------------------------------------
// Fused stage 2+3 v7s: v7 (verified 116.8 us) + s_setprio around MFMA
// clusters (T5 probe; pure scheduling hint, no semantic change).
// Quarter-K ping-pong pipeline, 256B-pitch 2-row-packed zero-conflict LDS,
// block tile 128 ml x 128 d, 4 waves (2x2), wave tile 64x64. permlane32_swap
// in-register transpose feeds stage3 (WtF fragments). Swizzled-LDS epilogue.
// ---------------------------------------------------------------------------
__global__ __launch_bounds__(256, 2) void fused_s23(
    const ushort* __restrict__ T1, const ushort* __restrict__ Gt,
    const ushort* __restrict__ WtF, const float* __restrict__ bias,
    float* __restrict__ out) {
  __shared__ ulong2 LDSQ[4096];              // 64 KB
  char* base = (char*)LDSQ;

  const int tid = threadIdx.x;
  const int f = blockIdx.x;                  // 1024 blocks
  const int lid = (f & 7) * 128 + (f >> 3);  // XCD-contiguous logical id
  const int dblk = lid & 1;
  const int mp   = (lid >> 1) & 63;
  const int b    = lid >> 7;

  const int lane = tid & 63;
  const int w  = tid >> 6;
  const int l5 = lane & 31;
  const int h5 = lane >> 5;
  const int wml = (w >> 1) * 64;             // wave ml-base in tile
  const int wd  = (w & 1) * 64;              // wave d-base in tile
  const int d0  = dblk * 128;

  const ushort* t1b  = T1 + ((size_t)b * 3) * SL + (size_t)mp * 128 * 256;
  const ushort* gtb0 = Gt + (size_t)d0 * NN;

  auto stage = [&](int t, int qb) {
    const int kj = t >> 2, q = t & 3;
    const int k = (kj >= 6) ? 2 : (kj >= 3 ? 1 : 0);
    const int j = kj - k * 3;
    const ushort* t1k = t1b + (size_t)k * SL + q * 64;
    const ushort* gtj = gtb0 + (size_t)j * NN * NN + q * 64;
    char* d1 = base + qb + ((tid & 192) << 4);
    char* d2 = d1 + 16384;
#pragma unroll
    for (int i = 0; i < 4; ++i) {
      const int gl = i * 256 + tid;          // linear granule 0..1023
      const int R  = gl >> 4;
      const int sd = (gl & 15) ^ (R & 15);   // data slot at this position
      const int dr = 2 * R + (sd >> 3);      // data row 0..127
      const int g  = sd & 7;                 // 16B granule within 64 cols
      gld_lds16(t1k + (size_t)dr * 256 + g * 8, d1 + (i << 12));
      gld_lds16(gtj + (size_t)dr * 256 + g * 8, d2 + (i << 12));
    }
  };
  auto ldv = [&](int qb, int toff, int row, int gq) -> short8v {
    const int R = row >> 1;
    const int s = (((row & 1) << 3) + gq) ^ (R & 15);
    return *(const short8v*)(base + qb + toff + (((R << 4) + s) << 4));
  };

  float16v acc3[2][2][2] = {};   // [msub][dsub][hb]
  float16v acc2[2][2] = {};      // [msub][dsub]

  stage(0, 0);                   // prologue

  for (int t = 0; t < 36; ++t) {
    const int qb = (t & 1) << 15;
    __syncthreads();             // tile t drained & visible; buf^1 reads done
    if (t + 1 < 36) stage(t + 1, qb ^ 32768);

    // ---- compute quarter: 4 K-steps x 4 MFMA (shared af/bf)
    __builtin_amdgcn_s_setprio(1);
#pragma unroll
    for (int ks = 0; ks < 4; ++ks) {
      const int gq = 2 * ks + h5;
      short8v af0 = ldv(qb, 0,     wml + l5,      gq);
      short8v af1 = ldv(qb, 0,     wml + 32 + l5, gq);
      short8v bf0 = ldv(qb, 16384, wd + l5,       gq);
      short8v bf1 = ldv(qb, 16384, wd + 32 + l5,  gq);
      acc2[0][0] = __builtin_amdgcn_mfma_f32_32x32x16_bf16(af0, bf0, acc2[0][0], 0, 0, 0);
      acc2[0][1] = __builtin_amdgcn_mfma_f32_32x32x16_bf16(af0, bf1, acc2[0][1], 0, 0, 0);
      acc2[1][0] = __builtin_amdgcn_mfma_f32_32x32x16_bf16(af1, bf0, acc2[1][0], 0, 0, 0);
      acc2[1][1] = __builtin_amdgcn_mfma_f32_32x32x16_bf16(af1, bf1, acc2[1][1], 0, 0, 0);
    }
    __builtin_amdgcn_s_setprio(0);

    if ((t & 3) == 3) {
      const int kj = t >> 2;
      // ---- stage3 A-frags (coalesced 1KB wave loads from L2-hot WtF)
      short8v Af[2][2];          // [kp][hb]
#pragma unroll
      for (int kp = 0; kp < 2; ++kp)
#pragma unroll
        for (int hb = 0; hb < 2; ++hb)
          Af[kp][hb] = *(const short8v*)(WtF +
              ((size_t)(((kj * 2 + kp) * 2 + hb) * 64 + lane)) * 8);

      // ---- per C2 tile: transpose via v_permlane32_swap -> stage3 B -> MFMA
      __builtin_amdgcn_s_setprio(1);
#pragma unroll
      for (int ms = 0; ms < 2; ++ms) {
#pragma unroll
        for (int ds = 0; ds < 2; ++ds) {
          uint P[8];
#pragma unroll
          for (int q = 0; q < 8; ++q)
            P[q] = packbf(acc2[ms][ds][2 * q], acc2[ms][ds][2 * q + 1]);
          short8v Bf[2];
#pragma unroll
          for (int kp = 0; kp < 2; ++kp) {
            uint a0 = P[4 * kp + 0], b0 = P[4 * kp + 2];
            uint a1 = P[4 * kp + 1], b1 = P[4 * kp + 3];
            asm("v_permlane32_swap_b32 %0, %1" : "+v"(a0), "+v"(b0));
            asm("v_permlane32_swap_b32 %0, %1" : "+v"(a1), "+v"(b1));
            uint4 u;
            u.x = a0; u.y = a1; u.z = b0; u.w = b1;
            Bf[kp] = *(short8v*)&u;
          }
#pragma unroll
          for (int hb = 0; hb < 2; ++hb) {
#pragma unroll
            for (int kp = 0; kp < 2; ++kp)
              acc3[ms][ds][hb] = __builtin_amdgcn_mfma_f32_32x32x16_bf16(
                  Af[kp][hb], Bf[kp], acc3[ms][ds][hb], 0, 0, 0);
          }
          // zero acc2 for next (k,j)
#pragma unroll
          for (int q = 0; q < 16; ++q) acc2[ms][ds][q] = 0.f;
        }
      }
      __builtin_amdgcn_s_setprio(0);
    }
  }

  // ---- epilogue: 2 passes of 2 m each; stage fp32 in swizzled LDS, then
  //      fully-coalesced stores with bias+ReLU.
  float4* EP = (float4*)base;    // [ml 2][d 128][hgran 16] float4 = 64 KB
#pragma unroll
  for (int mlp = 0; mlp < 2; ++mlp) {
    __syncthreads();             // LDS free / prior pass consumed
    if ((w >> 1) == mlp) {
#pragma unroll
      for (int ms = 0; ms < 2; ++ms) {
#pragma unroll
        for (int ds = 0; ds < 2; ++ds) {
          const int d = wd + ds * 32 + l5;
#pragma unroll
          for (int hb = 0; hb < 2; ++hb) {
#pragma unroll
            for (int s = 0; s < 4; ++s) {
              const int hg = 2 * s + h5 + 8 * hb;   // float4 granule of h
              float4 v;
              v.x = acc3[ms][ds][hb][4 * s + 0];
              v.y = acc3[ms][ds][hb][4 * s + 1];
              v.z = acc3[ms][ds][hb][4 * s + 2];
              v.w = acc3[ms][ds][hb][4 * s + 3];
              EP[(ms * 128 + d) * 16 + (hg ^ (d & 15))] = v;
            }
          }
        }
      }
    }
    __syncthreads();
    // coalesced store of 2 m rows (2 x 32 KB)
#pragma unroll
    for (int ii = 0; ii < 16; ++ii) {
      const int fi = tid + ii * 256;         // 0..4095 float4
      const int ml = fi >> 11;
      const int d  = (fi >> 4) & 127;
      const int hg = fi & 15;
      float4 v = EP[(ml * 128 + d) * 16 + (hg ^ (d & 15))];
      const float4 bb = *(const float4*)(bias + hg * 4);
      v.x = fmaxf(v.x + bb.x, 0.f);
      v.y = fmaxf(v.y + bb.y, 0.f);
      v.z = fmaxf(v.z + bb.z, 0.f);
      v.w = fmaxf(v.w + bb.w, 0.f);
      const int m = mp * 4 + mlp * 2 + ml;
      float* ob = out + (((size_t)b * NN + m) * NN + d0 + d) * NH;
      *(float4*)(ob + hg * 4) = v;
    }
  }
}

extern "C" void kernel_launch(void* const* d_in, const int* in_sizes, int n_in,
                              void* d_out, int out_size, void* d_ws, size_t ws_size,
                              hipStream_t stream) {
  (void)in_sizes; (void)n_in; (void)out_size; (void)ws_size;
  const float* X    = (const float*)d_in[0];
  const float* G    = (const float*)d_in[1];
  const float* W    = (const float*)d_in[2];
  const float* bias = (const float*)d_in[3];
  float* out = (float*)d_out;

  char* p = (char*)d_ws;
  ushort* Gt  = (ushort*)p;  p += (size_t)3 * NN * NN * 2;  // 384 KB
  ushort* WtF = (ushort*)p;  p += (size_t)64 * 1024;        // 36.9 KB (padded)
  ushort* Xt  = (ushort*)p;  p += (size_t)NB * SL * 2;      // 33.5 MB
  ushort* T1  = (ushort*)p;                                 // 100.7 MB

  prep_g<<<dim3(8, 8, 3), 256, 0, stream>>>(G, Gt);
  prep_wf<<<dim3(1), 256, 0, stream>>>(W, WtF);
  prep_x<<<dim3(256, 8, NB), 256, 0, stream>>>(X, Xt);

  // Stage 1 for all (b,k): z = b*3+k ; A = Gt[k], B = Xt[b], C = T1[z]
  gemm2<<<dim3(NQ / 128, NN / 128, 24), 256, 0, stream>>>(Gt, Xt, T1);

  // Fused stage 2+3 (1024 logical blocks, XCD-swizzled)
  fused_s23<<<dim3(1024), 256, 0, stream>>>(T1, Gt, WtF, bias, out);
}

// Round 16
// 195.080 us; speedup vs baseline: 1.0155x; 1.0155x over previous
//
#include <hip/hip_runtime.h>
#include <hip/hip_bf16.h>

#define NB 8
#define NN 256
#define NL 32
#define NQ 8192              // NN*NL
#define NH 64
#define SL ((size_t)NQ * NN) // elements per (b,k) T1 slab

typedef __attribute__((ext_vector_type(8))) short short8v;
typedef __attribute__((ext_vector_type(4))) float float4v;
typedef __attribute__((ext_vector_type(16))) float float16v;

static __device__ __forceinline__ ushort f2bf(float f) {
  __hip_bfloat16 h = __float2bfloat16(f);
  return *reinterpret_cast<const ushort*>(&h);
}
static __device__ __forceinline__ uint packbf(float a, float b) {
  return (uint)f2bf(a) | ((uint)f2bf(b) << 16);
}
static __device__ __forceinline__ void gld_lds16(const void* g, void* l) {
  __builtin_amdgcn_global_load_lds(
      (const __attribute__((address_space(1))) unsigned int*)g,
      (__attribute__((address_space(3))) unsigned int*)l, 16, 0, 0);
}

// ---------------------------------------------------------------------------
// Gt[k][m][n] = bf16(G[k][n][m])
// ---------------------------------------------------------------------------
__global__ __launch_bounds__(256) void prep_g(const float* __restrict__ G,
                                              ushort* __restrict__ Gt) {
  __shared__ float t[32][33];
  const int k = blockIdx.z, m0 = blockIdx.x * 32, n0 = blockIdx.y * 32;
  const int tid = threadIdx.x;
  const int c = tid & 31, r8 = tid >> 5;
#pragma unroll
  for (int i = 0; i < 4; ++i) {
    int r = r8 + i * 8;
    t[r][c] = G[((size_t)k * NN + n0 + r) * NN + m0 + c];
  }
  __syncthreads();
#pragma unroll
  for (int i = 0; i < 4; ++i) {
    int rm = r8 + i * 8;
    Gt[((size_t)k * NN + m0 + rm) * NN + n0 + c] = f2bf(t[c][rm]);
  }
}

// ---------------------------------------------------------------------------
// WtF: stage-3 A fragments in lane order. Entry e = ((kj*2+kp)*2+hb)*64+lane,
// 16B granule = 8 bf16 of W rows (kj*32+kp*16+(lane>>5)*8 + 0..7), col h.
// ---------------------------------------------------------------------------
__global__ __launch_bounds__(256) void prep_wf(const float* __restrict__ W,
                                               ushort* __restrict__ WtF) {
  const int tid = threadIdx.x;
  for (int e = tid; e < 9 * 2 * 2 * 64; e += 256) {
    const int ln = e & 63, hb = (e >> 6) & 1, kp = (e >> 7) & 1, kj = e >> 8;
    const int h = hb * 32 + (ln & 31);
    const int c0 = kj * 32 + kp * 16 + (ln >> 5) * 8;
    ushort v[8];
#pragma unroll
    for (int i = 0; i < 8; ++i) v[i] = f2bf(W[(size_t)(c0 + i) * NH + h]);
    *(ulong2*)(WtF + (size_t)e * 8) = *(ulong2*)v;
  }
}

// ---------------------------------------------------------------------------
// Xt[b][q'][n] = bf16(X[b][n][q]),  q = c*32+l,  q' = l*256+c
// ---------------------------------------------------------------------------
__global__ __launch_bounds__(256) void prep_x(const float* __restrict__ X,
                                              ushort* __restrict__ Xt) {
  __shared__ float t[32][33];
  const int qt = blockIdx.x;
  const int n0 = blockIdx.y * 32;
  const int b  = blockIdx.z;
  const int tid = threadIdx.x;
  const int c = tid & 31, r8 = tid >> 5;
  const float* Xb = X + (size_t)b * NN * NQ;
  ushort* Xo = Xt + (size_t)b * SL;
  const size_t q0 = (size_t)qt * 32;
#pragma unroll
  for (int i = 0; i < 4; ++i) {
    int r = r8 + i * 8;
    t[r][c] = Xb[(size_t)(n0 + r) * NQ + q0 + c];
  }
  __syncthreads();
#pragma unroll
  for (int i = 0; i < 4; ++i) {
    int l = r8 + i * 8;
    Xo[((size_t)l * NN + qt) * NN + n0 + c] = f2bf(t[c][l]);
  }
}

// ---------------------------------------------------------------------------
// Stage 1 GEMM v2 (gemm2): T1[z][m][q'] = Gt[z%3][m][:] . Xt[z/3][q'][:]
// Quarter-K ping-pong via global_load_lds, 256B-pitch 2-row-packed
// zero-conflict LDS, 4 waves (2x2), wave tile 64x64 of 32x32x16 MFMA.
// ---------------------------------------------------------------------------
__global__ __launch_bounds__(256, 2) void gemm2(
    const ushort* __restrict__ Gt, const ushort* __restrict__ Xt,
    ushort* __restrict__ T1) {
  __shared__ ulong2 LDSQ[4096];              // 64 KB
  char* base = (char*)LDSQ;

  const int tid = threadIdx.x;
  const int z = blockIdx.z;                  // b*3 + k
  const ushort* Ab = Gt + (size_t)(z % 3) * NN * NN +
                     (size_t)blockIdx.y * 128 * NN;
  const ushort* Bb = Xt + (size_t)(z / 3) * SL +
                     (size_t)blockIdx.x * 128 * NN;
  ushort* Cb = T1 + (size_t)z * SL;

  const int lane = tid & 63;
  const int w  = tid >> 6;
  const int l5 = lane & 31;
  const int h5 = lane >> 5;
  const int wr = (w >> 1) * 64;              // m within tile
  const int wc = (w & 1) * 64;               // q' within tile

  auto stage = [&](int q, int qb) {
    const ushort* a = Ab + q * 64;
    const ushort* bsrc = Bb + q * 64;
    char* d1 = base + qb + ((tid & 192) << 4);
    char* d2 = d1 + 16384;
#pragma unroll
    for (int i = 0; i < 4; ++i) {
      const int gl = i * 256 + tid;          // linear granule 0..1023
      const int R  = gl >> 4;
      const int sd = (gl & 15) ^ (R & 15);
      const int dr = 2 * R + (sd >> 3);      // data row 0..127
      const int g  = sd & 7;
      gld_lds16(a + (size_t)dr * 256 + g * 8, d1 + (i << 12));
      gld_lds16(bsrc + (size_t)dr * 256 + g * 8, d2 + (i << 12));
    }
  };
  auto ldv = [&](int qb, int toff, int row, int gq) -> short8v {
    const int R = row >> 1;
    const int s = (((row & 1) << 3) + gq) ^ (R & 15);
    return *(const short8v*)(base + qb + toff + (((R << 4) + s) << 4));
  };

  float16v acc[2][2] = {};

  stage(0, 0);

  for (int q = 0; q < 4; ++q) {
    const int qb = (q & 1) << 15;
    __syncthreads();
    if (q + 1 < 4) stage(q + 1, qb ^ 32768);
#pragma unroll
    for (int ks = 0; ks < 4; ++ks) {
      const int gq = 2 * ks + h5;
      short8v a0 = ldv(qb, 0,     wr + l5,      gq);
      short8v a1 = ldv(qb, 0,     wr + 32 + l5, gq);
      short8v b0 = ldv(qb, 16384, wc + l5,      gq);
      short8v b1 = ldv(qb, 16384, wc + 32 + l5, gq);
      acc[0][0] = __builtin_amdgcn_mfma_f32_32x32x16_bf16(a0, b0, acc[0][0], 0, 0, 0);
      acc[0][1] = __builtin_amdgcn_mfma_f32_32x32x16_bf16(a0, b1, acc[0][1], 0, 0, 0);
      acc[1][0] = __builtin_amdgcn_mfma_f32_32x32x16_bf16(a1, b0, acc[1][0], 0, 0, 0);
      acc[1][1] = __builtin_amdgcn_mfma_f32_32x32x16_bf16(a1, b1, acc[1][1], 0, 0, 0);
    }
  }

  // Epilogue: D-layout col = lane&31, row = (r&3) + 8*(r>>2) + 4*h5 (m101).
#pragma unroll
  for (int ms = 0; ms < 2; ++ms) {
#pragma unroll
    for (int ds = 0; ds < 2; ++ds) {
      ushort* cp = Cb +
          (size_t)(blockIdx.y * 128 + wr + ms * 32 + 4 * h5) * NQ +
          blockIdx.x * 128 + wc + ds * 32 + l5;
#pragma unroll
      for (int r = 0; r < 16; ++r) {
        const int row = (r & 3) + 8 * (r >> 2);
        cp[(size_t)row * NQ] = f2bf(acc[ms][ds][r]);
      }
    }
  }
}

// ---------------------------------------------------------------------------
// Fused stage 2+3 v7 (final, verified 116.8-117.3 us): quarter-K ping-pong
// pipeline, 256B-pitch 2-row-packed zero-conflict LDS, block tile
// 128 ml x 128 d, 4 waves (2x2), wave tile 64x64. permlane32_swap
// in-register transpose feeds stage3 (WtF fragments). Swizzled-LDS epilogue.
// ---------------------------------------------------------------------------
__global__ __launch_bounds__(256, 2) void fused_s23(
    const ushort* __restrict__ T1, const ushort* __restrict__ Gt,
    const ushort* __restrict__ WtF, const float* __restrict__ bias,
    float* __restrict__ out) {
  __shared__ ulong2 LDSQ[4096];              // 64 KB
  char* base = (char*)LDSQ;

  const int tid = threadIdx.x;
  const int f = blockIdx.x;                  // 1024 blocks
  const int lid = (f & 7) * 128 + (f >> 3);  // XCD-contiguous logical id
  const int dblk = lid & 1;
  const int mp   = (lid >> 1) & 63;
  const int b    = lid >> 7;

  const int lane = tid & 63;
  const int w  = tid >> 6;
  const int l5 = lane & 31;
  const int h5 = lane >> 5;
  const int wml = (w >> 1) * 64;             // wave ml-base in tile
  const int wd  = (w & 1) * 64;              // wave d-base in tile
  const int d0  = dblk * 128;

  const ushort* t1b  = T1 + ((size_t)b * 3) * SL + (size_t)mp * 128 * 256;
  const ushort* gtb0 = Gt + (size_t)d0 * NN;

  auto stage = [&](int t, int qb) {
    const int kj = t >> 2, q = t & 3;
    const int k = (kj >= 6) ? 2 : (kj >= 3 ? 1 : 0);
    const int j = kj - k * 3;
    const ushort* t1k = t1b + (size_t)k * SL + q * 64;
    const ushort* gtj = gtb0 + (size_t)j * NN * NN + q * 64;
    char* d1 = base + qb + ((tid & 192) << 4);
    char* d2 = d1 + 16384;
#pragma unroll
    for (int i = 0; i < 4; ++i) {
      const int gl = i * 256 + tid;          // linear granule 0..1023
      const int R  = gl >> 4;
      const int sd = (gl & 15) ^ (R & 15);   // data slot at this position
      const int dr = 2 * R + (sd >> 3);      // data row 0..127
      const int g  = sd & 7;                 // 16B granule within 64 cols
      gld_lds16(t1k + (size_t)dr * 256 + g * 8, d1 + (i << 12));
      gld_lds16(gtj + (size_t)dr * 256 + g * 8, d2 + (i << 12));
    }
  };
  auto ldv = [&](int qb, int toff, int row, int gq) -> short8v {
    const int R = row >> 1;
    const int s = (((row & 1) << 3) + gq) ^ (R & 15);
    return *(const short8v*)(base + qb + toff + (((R << 4) + s) << 4));
  };

  float16v acc3[2][2][2] = {};   // [msub][dsub][hb]
  float16v acc2[2][2] = {};      // [msub][dsub]

  stage(0, 0);                   // prologue

  for (int t = 0; t < 36; ++t) {
    const int qb = (t & 1) << 15;
    __syncthreads();             // tile t drained & visible; buf^1 reads done
    if (t + 1 < 36) stage(t + 1, qb ^ 32768);

    // ---- compute quarter: 4 K-steps x 4 MFMA (shared af/bf)
#pragma unroll
    for (int ks = 0; ks < 4; ++ks) {
      const int gq = 2 * ks + h5;
      short8v af0 = ldv(qb, 0,     wml + l5,      gq);
      short8v af1 = ldv(qb, 0,     wml + 32 + l5, gq);
      short8v bf0 = ldv(qb, 16384, wd + l5,       gq);
      short8v bf1 = ldv(qb, 16384, wd + 32 + l5,  gq);
      acc2[0][0] = __builtin_amdgcn_mfma_f32_32x32x16_bf16(af0, bf0, acc2[0][0], 0, 0, 0);
      acc2[0][1] = __builtin_amdgcn_mfma_f32_32x32x16_bf16(af0, bf1, acc2[0][1], 0, 0, 0);
      acc2[1][0] = __builtin_amdgcn_mfma_f32_32x32x16_bf16(af1, bf0, acc2[1][0], 0, 0, 0);
      acc2[1][1] = __builtin_amdgcn_mfma_f32_32x32x16_bf16(af1, bf1, acc2[1][1], 0, 0, 0);
    }

    if ((t & 3) == 3) {
      const int kj = t >> 2;
      // ---- stage3 A-frags (coalesced 1KB wave loads from L2-hot WtF)
      short8v Af[2][2];          // [kp][hb]
#pragma unroll
      for (int kp = 0; kp < 2; ++kp)
#pragma unroll
        for (int hb = 0; hb < 2; ++hb)
          Af[kp][hb] = *(const short8v*)(WtF +
              ((size_t)(((kj * 2 + kp) * 2 + hb) * 64 + lane)) * 8);

      // ---- per C2 tile: transpose via v_permlane32_swap -> stage3 B -> MFMA
#pragma unroll
      for (int ms = 0; ms < 2; ++ms) {
#pragma unroll
        for (int ds = 0; ds < 2; ++ds) {
          uint P[8];
#pragma unroll
          for (int q = 0; q < 8; ++q)
            P[q] = packbf(acc2[ms][ds][2 * q], acc2[ms][ds][2 * q + 1]);
          short8v Bf[2];
#pragma unroll
          for (int kp = 0; kp < 2; ++kp) {
            uint a0 = P[4 * kp + 0], b0 = P[4 * kp + 2];
            uint a1 = P[4 * kp + 1], b1 = P[4 * kp + 3];
            asm("v_permlane32_swap_b32 %0, %1" : "+v"(a0), "+v"(b0));
            asm("v_permlane32_swap_b32 %0, %1" : "+v"(a1), "+v"(b1));
            uint4 u;
            u.x = a0; u.y = a1; u.z = b0; u.w = b1;
            Bf[kp] = *(short8v*)&u;
          }
#pragma unroll
          for (int hb = 0; hb < 2; ++hb) {
#pragma unroll
            for (int kp = 0; kp < 2; ++kp)
              acc3[ms][ds][hb] = __builtin_amdgcn_mfma_f32_32x32x16_bf16(
                  Af[kp][hb], Bf[kp], acc3[ms][ds][hb], 0, 0, 0);
          }
          // zero acc2 for next (k,j)
#pragma unroll
          for (int q = 0; q < 16; ++q) acc2[ms][ds][q] = 0.f;
        }
      }
    }
  }

  // ---- epilogue: 2 passes of 2 m each; stage fp32 in swizzled LDS, then
  //      fully-coalesced stores with bias+ReLU.
  float4* EP = (float4*)base;    // [ml 2][d 128][hgran 16] float4 = 64 KB
#pragma unroll
  for (int mlp = 0; mlp < 2; ++mlp) {
    __syncthreads();             // LDS free / prior pass consumed
    if ((w >> 1) == mlp) {
#pragma unroll
      for (int ms = 0; ms < 2; ++ms) {
#pragma unroll
        for (int ds = 0; ds < 2; ++ds) {
          const int d = wd + ds * 32 + l5;
#pragma unroll
          for (int hb = 0; hb < 2; ++hb) {
#pragma unroll
            for (int s = 0; s < 4; ++s) {
              const int hg = 2 * s + h5 + 8 * hb;   // float4 granule of h
              float4 v;
              v.x = acc3[ms][ds][hb][4 * s + 0];
              v.y = acc3[ms][ds][hb][4 * s + 1];
              v.z = acc3[ms][ds][hb][4 * s + 2];
              v.w = acc3[ms][ds][hb][4 * s + 3];
              EP[(ms * 128 + d) * 16 + (hg ^ (d & 15))] = v;
            }
          }
        }
      }
    }
    __syncthreads();
    // coalesced store of 2 m rows (2 x 32 KB)
#pragma unroll
    for (int ii = 0; ii < 16; ++ii) {
      const int fi = tid + ii * 256;         // 0..4095 float4
      const int ml = fi >> 11;
      const int d  = (fi >> 4) & 127;
      const int hg = fi & 15;
      float4 v = EP[(ml * 128 + d) * 16 + (hg ^ (d & 15))];
      const float4 bb = *(const float4*)(bias + hg * 4);
      v.x = fmaxf(v.x + bb.x, 0.f);
      v.y = fmaxf(v.y + bb.y, 0.f);
      v.z = fmaxf(v.z + bb.z, 0.f);
      v.w = fmaxf(v.w + bb.w, 0.f);
      const int m = mp * 4 + mlp * 2 + ml;
      float* ob = out + (((size_t)b * NN + m) * NN + d0 + d) * NH;
      *(float4*)(ob + hg * 4) = v;
    }
  }
}

extern "C" void kernel_launch(void* const* d_in, const int* in_sizes, int n_in,
                              void* d_out, int out_size, void* d_ws, size_t ws_size,
                              hipStream_t stream) {
  (void)in_sizes; (void)n_in; (void)out_size; (void)ws_size;
  const float* X    = (const float*)d_in[0];
  const float* G    = (const float*)d_in[1];
  const float* W    = (const float*)d_in[2];
  const float* bias = (const float*)d_in[3];
  float* out = (float*)d_out;

  char* p = (char*)d_ws;
  ushort* Gt  = (ushort*)p;  p += (size_t)3 * NN * NN * 2;  // 384 KB
  ushort* WtF = (ushort*)p;  p += (size_t)64 * 1024;        // 36.9 KB (padded)
  ushort* Xt  = (ushort*)p;  p += (size_t)NB * SL * 2;      // 33.5 MB
  ushort* T1  = (ushort*)p;                                 // 100.7 MB

  prep_g<<<dim3(8, 8, 3), 256, 0, stream>>>(G, Gt);
  prep_wf<<<dim3(1), 256, 0, stream>>>(W, WtF);
  prep_x<<<dim3(256, 8, NB), 256, 0, stream>>>(X, Xt);

  // Stage 1 for all (b,k): z = b*3+k ; A = Gt[k], B = Xt[b], C = T1[z]
  gemm2<<<dim3(NQ / 128, NN / 128, 24), 256, 0, stream>>>(Gt, Xt, T1);

  // Fused stage 2+3 (1024 logical blocks, XCD-swizzled)
  fused_s23<<<dim3(1024), 256, 0, stream>>>(T1, Gt, WtF, bias, out);
}